// Round 8
// baseline (3816.163 us; speedup 1.0000x reference)
//
#include <hip/hip_runtime.h>
#include <hip/hip_bf16.h>

typedef __attribute__((ext_vector_type(8))) short bf16x8;
typedef __attribute__((ext_vector_type(4))) float f32x4;
typedef __attribute__((ext_vector_type(4))) unsigned u32x4;
typedef __attribute__((ext_vector_type(2))) unsigned u32x2;

#define SEQT 2048
#define BATCH 32
#define INDIM 512
#define EMB 256
#define HHX 128
#define LBL 16
#define LOG2E 1.44269504f

__device__ __forceinline__ unsigned short f2bf(float f) {
    unsigned u = __float_as_uint(f);
    u += 0x7FFFu + ((u >> 16) & 1u);
    return (unsigned short)(u >> 16);
}
#define BLO(u) __uint_as_float((u) << 16)
#define BHI(u) __uint_as_float((u) & 0xffff0000u)

// Fused-denominator cell: 5 exp2 + 2 rcp. Inputs pre-scaled (-LOG2E for i,f,o;
// +2*LOG2E for g). Clamps keep every factor finite -> NaN-proof saturation.
__device__ __forceinline__ float cell(float ig, float fg, float gg, float og, float& c) {
    float Ef = __builtin_amdgcn_exp2f(fminf(fg, 30.f));
    float Ei = __builtin_amdgcn_exp2f(fminf(ig, 30.f));
    float Eg = __builtin_amdgcn_exp2f(fminf(gg, 60.f));
    float Eo = __builtin_amdgcn_exp2f(fminf(og, 30.f));
    float pf = 1.f + Ef;
    float t1 = (Eg + 1.f) * (1.f + Ei);
    float num = c * t1 + (Eg - 1.f) * pf;
    float cn = num * __builtin_amdgcn_rcpf(pf * t1);
    c = cn;
    float E2 = __builtin_amdgcn_exp2f(fminf(2.f * LOG2E * cn, 60.f));
    float r3 = __builtin_amdgcn_rcpf((E2 + 1.f) * (1.f + Eo));
    return (E2 - 1.f) * r3;
}

// Transposed-tile gate-row permutation:
// perm row R (0..511): tile=R>>4, r=R&15, unit=tile*4+(r>>2), gate=r&3 (i,f,g,o)
// orig row = gate*128 + unit
__device__ __forceinline__ int orig_of(int R) {
    int r = R & 15;
    return (r & 3) * 128 + (R >> 4) * 4 + (r >> 2);
}
__device__ __forceinline__ float gate_scale(int R) {
    return ((R & 3) == 2) ? (2.f * LOG2E) : (-LOG2E);
}

// ---------------- prep: combined W (Wih @ in_W) + bias, permuted+scaled rows ----------------
__global__ __launch_bounds__(256) void k_prep_wc(
    const float* __restrict__ in_W, const float* __restrict__ in_b,
    const float* __restrict__ Wih_f, const float* __restrict__ b_f,
    const float* __restrict__ Wih_b, const float* __restrict__ b_b,
    unsigned short* __restrict__ Wc, float* __restrict__ bc)
{
    int G0 = blockIdx.x * 8;         // 128 blocks
    int tid = threadIdx.x;
    __shared__ float wrow[8][EMB];
    for (int e = tid; e < 8 * EMB; e += 256) {
        int r = e >> 8, ee = e & 255;
        int G = G0 + r, dir = G >> 9, gp = G & 511;
        wrow[r][ee] = (dir ? Wih_b : Wih_f)[orig_of(gp) * EMB + ee] * gate_scale(gp);
    }
    __syncthreads();
    for (int k = tid; k < INDIM; k += 256) {
        float acc[8] = {0, 0, 0, 0, 0, 0, 0, 0};
        #pragma unroll 4
        for (int e = 0; e < EMB; ++e) {
            float x = in_W[e * INDIM + k];
            #pragma unroll
            for (int r = 0; r < 8; ++r) acc[r] += wrow[r][e] * x;
        }
        #pragma unroll
        for (int r = 0; r < 8; ++r) Wc[(size_t)(G0 + r) * INDIM + k] = f2bf(acc[r]);
    }
    if (tid < 64) {
        for (int r = 0; r < 8; ++r) {
            float p = 0.f;
            for (int e = tid; e < EMB; e += 64) p += wrow[r][e] * in_b[e];
            for (int off = 32; off; off >>= 1) p += __shfl_xor(p, off);
            if (tid == 0) {
                int G = G0 + r, dir = G >> 9, gp = G & 511;
                bc[G] = (dir ? b_b : b_f)[orig_of(gp)] * gate_scale(gp) + p;
            }
        }
    }
}

// ---------------- prep: bf16 converts (Whh permuted+scaled, out_W unit-permuted) ----------------
__global__ __launch_bounds__(256) void k_prep_misc(
    const float* __restrict__ Whh_f, const float* __restrict__ Whh_b,
    const float* __restrict__ out_W,
    unsigned short* __restrict__ Whh_bf, unsigned short* __restrict__ outW_bf)
{
    int idx = blockIdx.x * 256 + threadIdx.x;
    int stride = gridDim.x * 256;
    for (int i = idx; i < 1024 * HHX; i += stride) {
        int G = i >> 7, k = i & 127;
        int dir = G >> 9, gp = G & 511;
        const float* Whh = dir ? Whh_b : Whh_f;
        Whh_bf[i] = f2bf(Whh[orig_of(gp) * HHX + k] * gate_scale(gp));
    }
    // outW permuted to match H's stored unit order: pos = w*32 + lq*8 + t2
    // holds source unit w*32 + t2*4 + lq (within each dir-half).
    for (int i = idx; i < LBL * 256; i += stride) {
        int lbl = i >> 8, pos = i & 255;
        int half = pos & 128, p7 = pos & 127;
        int w5 = p7 >> 5, r = p7 & 31, lq = r >> 3, t2 = r & 7;
        int src = half + w5 * 32 + t2 * 4 + lq;
        outW_bf[i] = f2bf(out_W[lbl * 256 + src]);
    }
}

// ---------------- big GEMM (flipped): C[1024 perm-gate-rows][65536 m] = Wc @ S^T + bc ----------------
// Epilogue: lane's f32x4 = 4 gates (i,f,g,o) of one unit -> u32x2 store into
// P2[(ts*4 + dir*2 + bt)][tid(256) = w2*64 + lq*16 + batch][32 = t2*4 + q]
__global__ __launch_bounds__(512) void k_gemm_p(
    const float* __restrict__ S, const unsigned short* __restrict__ Wc,
    const float* __restrict__ bc, unsigned short* __restrict__ P2)
{
    int m0g = blockIdx.y * 256;      // perm gate rows
    int n0 = blockIdx.x * 64;        // m = t*32 + b
    int tid = threadIdx.x;
    int w = tid >> 6, l = tid & 63;
    int lr = l & 15, lq = l >> 4;
    int wm = w >> 1, wn = w & 1;     // 4 gate-wave-tiles x 2 m-wave-tiles

    __shared__ __align__(16) unsigned short Alds[256 * 64];  // gates x k
    __shared__ __align__(16) unsigned short Blds[64 * 64];   // m x k

    const f32x4 fzero = {0.f, 0.f, 0.f, 0.f};
    f32x4 acc[4][2];
    #pragma unroll
    for (int a = 0; a < 4; ++a)
        #pragma unroll
        for (int b = 0; b < 2; ++b) acc[a][b] = fzero;

    for (int kt = 0; kt < 8; ++kt) {
        { // stage A: Wc rows (bf16), XOR-swizzled 128B rows
            int r = tid >> 1, h2 = tid & 1;
            const unsigned short* as = Wc + (size_t)(m0g + r) * INDIM + kt * 64;
            #pragma unroll
            for (int cc = 0; cc < 4; ++cc) {
                int ch = h2 * 4 + cc;
                bf16x8 v = *(const bf16x8*)(as + ch * 8);
                *(bf16x8*)((char*)Alds + r * 128 + ((ch * 16) ^ ((r & 7) << 4))) = v;
            }
        }
        { // stage B: S rows (fp32 -> bf16 via cvt_pk)
            int r = tid >> 3, c = tid & 7;
            const float* src = S + (size_t)(n0 + r) * INDIM + kt * 64 + c * 8;
            float4 v0 = *(const float4*)src;
            float4 v1 = *(const float4*)(src + 4);
            unsigned g0, g1, g2, g3;
            asm("v_cvt_pk_bf16_f32 %0, %1, %2" : "=v"(g0) : "v"(v0.x), "v"(v0.y));
            asm("v_cvt_pk_bf16_f32 %0, %1, %2" : "=v"(g1) : "v"(v0.z), "v"(v0.w));
            asm("v_cvt_pk_bf16_f32 %0, %1, %2" : "=v"(g2) : "v"(v1.x), "v"(v1.y));
            asm("v_cvt_pk_bf16_f32 %0, %1, %2" : "=v"(g3) : "v"(v1.z), "v"(v1.w));
            u32x4 wv = {g0, g1, g2, g3};
            *(u32x4*)((char*)Blds + r * 128 + ((c * 16) ^ ((r & 7) << 4))) = wv;
        }
        __syncthreads();
        bf16x8 afr[4][2], bfr[2][2];
        #pragma unroll
        for (int tg = 0; tg < 4; ++tg)
            #pragma unroll
            for (int kk = 0; kk < 2; ++kk) {
                int ra = wm * 64 + tg * 16 + lr;
                afr[tg][kk] = *(const bf16x8*)((char*)Alds + ra * 128 + ((kk * 64 + lq * 16) ^ ((ra & 7) << 4)));
            }
        #pragma unroll
        for (int tb = 0; tb < 2; ++tb)
            #pragma unroll
            for (int kk = 0; kk < 2; ++kk) {
                int rb = wn * 32 + tb * 16 + lr;
                bfr[tb][kk] = *(const bf16x8*)((char*)Blds + rb * 128 + ((kk * 64 + lq * 16) ^ ((rb & 7) << 4)));
            }
        #pragma unroll
        for (int tg = 0; tg < 4; ++tg)
            #pragma unroll
            for (int tb = 0; tb < 2; ++tb)
                #pragma unroll
                for (int kk = 0; kk < 2; ++kk)
                    acc[tg][tb] = __builtin_amdgcn_mfma_f32_16x16x32_bf16(afr[tg][kk], bfr[tb][kk], acc[tg][tb], 0, 0, 0);
        __syncthreads();
    }
    // epilogue: R = perm gate row base; j = gate q; lane col = m
    #pragma unroll
    for (int tg = 0; tg < 4; ++tg) {
        int R = m0g + wm * 64 + tg * 16 + lq * 4;
        float4 b4 = *(const float4*)(bc + R);
        int dir = R >> 9, R9 = R & 511;
        int tile = R9 >> 4;
        int w2 = tile >> 3, t2 = tile & 7;
        #pragma unroll
        for (int tb = 0; tb < 2; ++tb) {
            int mcol = n0 + wn * 32 + tb * 16 + lr;
            int ts = mcol >> 5, bt = (mcol >> 4) & 1, bb = mcol & 15;
            size_t base = ((size_t)(ts * 4 + dir * 2 + bt) * 256 + w2 * 64 + lq * 16 + bb) * 32 + t2 * 4;
            float f0 = acc[tg][tb][0] + b4.x, f1 = acc[tg][tb][1] + b4.y;
            float f2 = acc[tg][tb][2] + b4.z, f3 = acc[tg][tb][3] + b4.w;
            unsigned p01, p23;
            asm("v_cvt_pk_bf16_f32 %0, %1, %2" : "=v"(p01) : "v"(f0), "v"(f1));
            asm("v_cvt_pk_bf16_f32 %0, %1, %2" : "=v"(p23) : "v"(f2), "v"(f3));
            *(u32x2*)(P2 + base) = (u32x2){p01, p23};
        }
    }
}

// ---------------- LSTM recurrence: 4 blocks (dir x bt16) x 256 threads (4 waves) ----------------
// Transposed MFMA: A = Whh_perm (in regs), B = h^T from LDS. Each lane owns 8 cells
// (units w*32 + t2*4 + lq, batch lr); all 4 gates land in its f32x4 -> no shuffle.
__global__ __launch_bounds__(256, 1) void k_lstm(
    const unsigned short* __restrict__ P2, const unsigned short* __restrict__ Whh_bf,
    const float* __restrict__ h0, const float* __restrict__ c0,
    unsigned short* __restrict__ H)
{
    int blk = blockIdx.x;
    int dir = blk >> 1, bt = blk & 1;
    int tid = threadIdx.x;
    int w = tid >> 6, l = tid & 63;   // w: 0..3
    int lr = l & 15, lq = l >> 4;

    __shared__ __align__(16) unsigned short hbuf[2][16 * 128];  // [batch16][unit128]
    char* hb = (char*)hbuf;

    // A-frags: 8 tiles x 4 k-frags (128 VGPR), loaded once
    bf16x8 afr[8][4];
    #pragma unroll
    for (int t2 = 0; t2 < 8; ++t2)
        #pragma unroll
        for (int ko = 0; ko < 4; ++ko) {
            int row = dir * 512 + (w * 8 + t2) * 16 + lr;
            afr[t2][ko] = *(const bf16x8*)(Whh_bf + (size_t)row * HHX + ko * 32 + lq * 8);
        }

    float c_reg[8];
    #pragma unroll
    for (int t2 = 0; t2 < 8; ++t2)
        c_reg[t2] = c0[(dir * 32 + bt * 16 + lr) * HHX + w * 32 + t2 * 4 + lq];

    for (int e = tid; e < 2048; e += 256) {
        int b = e >> 7, u = e & 127;
        float hv = h0[(dir * 32 + bt * 16 + b) * HHX + u];
        *(unsigned short*)(hb + ((b * 256 + u * 2) ^ ((b & 7) << 4))) = f2bf(hv);
    }
    __syncthreads();

    const int swz = (lr & 7) << 4;
    const int rd0 = (lr * 256 + 0 * 64 + lq * 16) ^ swz;
    const int rd1 = (lr * 256 + 1 * 64 + lq * 16) ^ swz;
    const int rd2 = (lr * 256 + 2 * 64 + lq * 16) ^ swz;
    const int rd3 = (lr * 256 + 3 * 64 + lq * 16) ^ swz;
    const int wa0 = (lr * 256 + (w * 32 + 0 * 4 + lq) * 2) ^ swz;
    const int wa1 = (lr * 256 + (w * 32 + 1 * 4 + lq) * 2) ^ swz;
    const int wa2 = (lr * 256 + (w * 32 + 2 * 4 + lq) * 2) ^ swz;
    const int wa3 = (lr * 256 + (w * 32 + 3 * 4 + lq) * 2) ^ swz;
    const int wa4 = (lr * 256 + (w * 32 + 4 * 4 + lq) * 2) ^ swz;
    const int wa5 = (lr * 256 + (w * 32 + 5 * 4 + lq) * 2) ^ swz;
    const int wa6 = (lr * 256 + (w * 32 + 6 * 4 + lq) * 2) ^ swz;
    const int wa7 = (lr * 256 + (w * 32 + 7 * 4 + lq) * 2) ^ swz;

    int t0 = dir ? (SEQT - 1) : 0;
    const long long pstep = (dir ? -1LL : 1LL) * (4LL * 256 * 32);
    const unsigned short* pptr = P2 + ((size_t)(t0 * 4 + dir * 2 + bt) * 256 + tid) * 32;
    bf16x8 pc0 = *(const bf16x8*)pptr;
    bf16x8 pc1 = *(const bf16x8*)(pptr + 8);
    bf16x8 pc2 = *(const bf16x8*)(pptr + 16);
    bf16x8 pc3 = *(const bf16x8*)(pptr + 24);
    pptr += pstep;

    unsigned short* hptr = H + (size_t)(t0 * 32 + bt * 16 + lr) * 256 + dir * 128 + w * 32 + lq * 8;
    const long long hstep = (dir ? -1LL : 1LL) * (32 * 256);

// LDS-only barrier (no vmcnt drain -> P prefetch + H stores stay in flight)
#define LBAR() asm volatile("s_waitcnt lgkmcnt(0)\n\ts_barrier" ::: "memory")

#define TILE(T2, WLO, WHI) \
    { \
        f32x4 aa = {BLO(WLO), BHI(WLO), BLO(WHI), BHI(WHI)}; \
        f32x4 ab = {0.f, 0.f, 0.f, 0.f}; \
        aa = __builtin_amdgcn_mfma_f32_16x16x32_bf16(afr[T2][0], bf0, aa, 0, 0, 0); \
        ab = __builtin_amdgcn_mfma_f32_16x16x32_bf16(afr[T2][2], bf2, ab, 0, 0, 0); \
        aa = __builtin_amdgcn_mfma_f32_16x16x32_bf16(afr[T2][1], bf1, aa, 0, 0, 0); \
        ab = __builtin_amdgcn_mfma_f32_16x16x32_bf16(afr[T2][3], bf3, ab, 0, 0, 0); \
        aa = aa + ab; \
        hn##T2 = cell(aa[0], aa[1], aa[2], aa[3], c_reg[T2]); \
    }

#define STEP(CUR, PF) do { \
    bf16x8 bf0 = *(const bf16x8*)(hb + (CUR) * 4096 + rd0); \
    bf16x8 bf1 = *(const bf16x8*)(hb + (CUR) * 4096 + rd1); \
    bf16x8 bf2 = *(const bf16x8*)(hb + (CUR) * 4096 + rd2); \
    bf16x8 bf3 = *(const bf16x8*)(hb + (CUR) * 4096 + rd3); \
    u32x4 q0 = __builtin_bit_cast(u32x4, pc0); \
    u32x4 q1 = __builtin_bit_cast(u32x4, pc1); \
    u32x4 q2 = __builtin_bit_cast(u32x4, pc2); \
    u32x4 q3 = __builtin_bit_cast(u32x4, pc3); \
    if (PF) { \
        pc0 = *(const bf16x8*)pptr; \
        pc1 = *(const bf16x8*)(pptr + 8); \
        pc2 = *(const bf16x8*)(pptr + 16); \
        pc3 = *(const bf16x8*)(pptr + 24); \
        pptr += pstep; \
    } \
    float hn0, hn1, hn2, hn3, hn4, hn5, hn6, hn7; \
    TILE(0, q0.x, q0.y) \
    TILE(1, q0.z, q0.w) \
    TILE(2, q1.x, q1.y) \
    TILE(3, q1.z, q1.w) \
    TILE(4, q2.x, q2.y) \
    TILE(5, q2.z, q2.w) \
    TILE(6, q3.x, q3.y) \
    TILE(7, q3.z, q3.w) \
    unsigned k01, k23, k45, k67; \
    asm("v_cvt_pk_bf16_f32 %0, %1, %2" : "=v"(k01) : "v"(hn0), "v"(hn1)); \
    asm("v_cvt_pk_bf16_f32 %0, %1, %2" : "=v"(k23) : "v"(hn2), "v"(hn3)); \
    asm("v_cvt_pk_bf16_f32 %0, %1, %2" : "=v"(k45) : "v"(hn4), "v"(hn5)); \
    asm("v_cvt_pk_bf16_f32 %0, %1, %2" : "=v"(k67) : "v"(hn6), "v"(hn7)); \
    char* wb = hb + (((CUR) ^ 1) * 4096); \
    *(unsigned short*)(wb + wa0) = (unsigned short)k01; \
    *(unsigned short*)(wb + wa1) = (unsigned short)(k01 >> 16); \
    *(unsigned short*)(wb + wa2) = (unsigned short)k23; \
    *(unsigned short*)(wb + wa3) = (unsigned short)(k23 >> 16); \
    *(unsigned short*)(wb + wa4) = (unsigned short)k45; \
    *(unsigned short*)(wb + wa5) = (unsigned short)(k45 >> 16); \
    *(unsigned short*)(wb + wa6) = (unsigned short)k67; \
    *(unsigned short*)(wb + wa7) = (unsigned short)(k67 >> 16); \
    *(u32x4*)hptr = (u32x4){k01, k23, k45, k67}; \
    hptr += hstep; \
    LBAR(); \
} while (0)

    for (int it = 0; it < 1023; ++it) {
        STEP(0, true);
        STEP(1, true);
    }
    STEP(0, true);
    STEP(1, false);
#undef STEP
#undef TILE
#undef LBAR
}

// ---------------- feats: F(65536x16) = H @ outW_perm^T + out_b ----------------
__global__ __launch_bounds__(256) void k_feats(
    const unsigned short* __restrict__ H, const unsigned short* __restrict__ outW_bf,
    const float* __restrict__ out_b, float* __restrict__ feats)
{
    int m0 = blockIdx.x * 64;
    int tid = threadIdx.x;
    int w = tid >> 6, l = tid & 63;
    int lr = l & 15, lq = l >> 4;
    __shared__ __align__(16) unsigned short Hl[64 * 256];

    {
        int r = tid >> 2, cb = (tid & 3) * 8;
        #pragma unroll
        for (int cc = 0; cc < 8; ++cc) {
            int c = cb + cc;
            bf16x8 v = *(const bf16x8*)(H + (size_t)(m0 + r) * 256 + c * 8);
            *(bf16x8*)((char*)Hl + r * 512 + ((c * 16) ^ ((r & 7) << 4))) = v;
        }
    }
    bf16x8 bw[8];
    #pragma unroll
    for (int ko = 0; ko < 8; ++ko)
        bw[ko] = *(const bf16x8*)(outW_bf + lr * 256 + ko * 32 + lq * 8);
    __syncthreads();
    int row = w * 16 + lr;
    f32x4 acc = {0.f, 0.f, 0.f, 0.f};
    #pragma unroll
    for (int ko = 0; ko < 8; ++ko) {
        bf16x8 a = *(const bf16x8*)((char*)Hl + row * 512 + ((ko * 64 + lq * 16) ^ ((row & 7) << 4)));
        acc = __builtin_amdgcn_mfma_f32_16x16x32_bf16(a, bw[ko], acc, 0, 0, 0);
    }
    float ob = out_b[lr];
    #pragma unroll
    for (int j = 0; j < 4; ++j) {
        int m = m0 + w * 16 + lq * 4 + j;
        feats[(size_t)m * 16 + lr] = acc[j] + ob;
    }
}

// ---------------- Viterbi: 1 block per batch, 1 wave; DPP reduce + packed backtrack ----------------
template <int CTRL>
__device__ __forceinline__ float dppf(float x) {
    return __int_as_float(__builtin_amdgcn_update_dpp(0, __float_as_int(x), CTRL, 0xF, 0xF, true));
}
template <int CTRL>
__device__ __forceinline__ int dppi(int x) {
    return __builtin_amdgcn_update_dpp(0, x, CTRL, 0xF, 0xF, true);
}

__global__ __launch_bounds__(64) void k_viterbi(
    const float* __restrict__ feats, const float* __restrict__ trans,
    float* __restrict__ out)
{
    int b = blockIdx.x;
    int l = threadIdx.x;
    int i = l >> 2, s = l & 3;          // i = next-label (0..15), s = prev-quad (0..3)
    __shared__ unsigned char bp[SEQT * 16];
    __shared__ __align__(16) float fch[256 * 16];
    __shared__ unsigned long long bp64[SEQT];

    float tr[4];
    #pragma unroll
    for (int m = 0; m < 4; ++m) tr[m] = trans[i * 16 + s * 4 + m];
    float fvloc[4];
    #pragma unroll
    for (int m = 0; m < 4; ++m) fvloc[m] = (s * 4 + m == 0) ? 0.f : -10000.f;

    int ga[4];
    #pragma unroll
    for (int m = 0; m < 4; ++m) ga[m] = (16 * s + 4 * m) * 4;   // bpermute byte addr

    for (int t = 0; t < SEQT; ++t) {
        if ((t & 255) == 0) {
            __syncthreads();
            for (int k = l; k < 256; k += 64) {
                const float4* src = (const float4*)(feats + (size_t)((t + k) * 32 + b) * 16);
                float4 v0 = src[0], v1 = src[1], v2 = src[2], v3 = src[3];
                float4* dst = (float4*)(fch + k * 16);
                dst[0] = v0; dst[1] = v1; dst[2] = v2; dst[3] = v3;
            }
            __syncthreads();
        }
        float best = fvloc[0] + tr[0];
        int bj = s * 4;
        #pragma unroll
        for (int m = 1; m < 4; ++m) {
            float v = fvloc[m] + tr[m];
            if (v > best) { best = v; bj = s * 4 + m; }
        }
        { // quad xor1 via DPP quad_perm [1,0,3,2]
            float ov = dppf<0xB1>(best); int oj = dppi<0xB1>(bj);
            bool take = (ov > best) || (ov == best && oj < bj);
            best = take ? ov : best; bj = take ? oj : bj;
        }
        { // quad xor2 via DPP quad_perm [2,3,0,1]
            float ov = dppf<0x4E>(best); int oj = dppi<0x4E>(bj);
            bool take = (ov > best) || (ov == best && oj < bj);
            best = take ? ov : best; bj = take ? oj : bj;
        }
        float fvn = best + fch[(t & 255) * 16 + i];
        if (s == 0) bp[t * 16 + i] = (unsigned char)bj;
        #pragma unroll
        for (int m = 0; m < 4; ++m)
            fvloc[m] = __int_as_float(__builtin_amdgcn_ds_bpermute(ga[m], __float_as_int(fvn)));
    }
    // termination
    float bestS = fvloc[0] + trans[16 + s * 4];
    int bl = s * 4;
    #pragma unroll
    for (int m = 1; m < 4; ++m) {
        float tv = fvloc[m] + trans[16 + s * 4 + m];
        if (tv > bestS) { bestS = tv; bl = s * 4 + m; }
    }
    {
        float ov = dppf<0xB1>(bestS); int oj = dppi<0xB1>(bl);
        bool take = (ov > bestS) || (ov == bestS && oj < bl);
        bestS = take ? ov : bestS; bl = take ? oj : bl;
    }
    {
        float ov = dppf<0x4E>(bestS); int oj = dppi<0x4E>(bl);
        bool take = (ov > bestS) || (ov == bestS && oj < bl);
        bestS = take ? ov : bestS; bl = take ? oj : bl;
    }
    __syncthreads();
    // pack bp rows into nibble-u64 (address-independent backtrack reads)
    for (int t = l; t < SEQT; t += 64) {
        const uint4* p = (const uint4*)(bp + t * 16);
        uint4 u = *p;
        unsigned n0 = (u.x | (u.x >> 4)) & 0x00FF00FFu; n0 = (n0 | (n0 >> 8)) & 0xFFFFu;
        unsigned n1 = (u.y | (u.y >> 4)) & 0x00FF00FFu; n1 = (n1 | (n1 >> 8)) & 0xFFFFu;
        unsigned n2 = (u.z | (u.z >> 4)) & 0x00FF00FFu; n2 = (n2 | (n2 >> 8)) & 0xFFFFu;
        unsigned n3 = (u.w | (u.w >> 4)) & 0x00FF00FFu; n3 = (n3 | (n3 >> 8)) & 0xFFFFu;
        bp64[t] = (unsigned long long)n0 | ((unsigned long long)n1 << 16)
                | ((unsigned long long)n2 << 32) | ((unsigned long long)n3 << 48);
    }
    __syncthreads();
    if (l == 0) out[b] = bestS;
    // all lanes run the chain redundantly; lane t&63 stores t
    int lbl = bl;
    #pragma unroll 8
    for (int t = SEQT - 1; t >= 0; --t) {
        if ((t & 63) == l) out[32 + (size_t)t * 32 + b] = (float)lbl;
        lbl = (int)((bp64[t] >> (lbl * 4)) & 15ull);
    }
}

extern "C" void kernel_launch(void* const* d_in, const int* in_sizes, int n_in,
                              void* d_out, int out_size, void* d_ws, size_t ws_size,
                              hipStream_t stream) {
    const float* source = (const float*)d_in[0];
    const float* in_W  = (const float*)d_in[1];
    const float* in_b  = (const float*)d_in[2];
    const float* Wih_f = (const float*)d_in[3];
    const float* Whh_f = (const float*)d_in[4];
    const float* b_f   = (const float*)d_in[5];
    const float* Wih_b = (const float*)d_in[6];
    const float* Whh_b = (const float*)d_in[7];
    const float* b_b   = (const float*)d_in[8];
    const float* out_W = (const float*)d_in[9];
    const float* out_b = (const float*)d_in[10];
    const float* trans = (const float*)d_in[11];
    const float* h0    = (const float*)d_in[12];
    const float* c0    = (const float*)d_in[13];
    float* out = (float*)d_out;

    char* ws = (char*)d_ws;
    unsigned short* P2      = (unsigned short*)(ws);                 // 2048*4*256*32*2 = 134217728
    unsigned short* H       = (unsigned short*)(ws + 134217728);     // 65536*256*2  =  33554432
    float*          feats   = (float*)         (ws + 167772160);     // 65536*16*4   =   4194304
    unsigned short* Wc      = (unsigned short*)(ws + 171966464);     // 1024*512*2   =   1048576
    float*          bc      = (float*)         (ws + 173015040);     // 1024*4
    unsigned short* Whh_bf  = (unsigned short*)(ws + 173019136);     // 1024*128*2   =    262144
    unsigned short* outW_bf = (unsigned short*)(ws + 173281280);     // 16*256*2
    // total ~173.3 MB

    hipLaunchKernelGGL(k_prep_wc, dim3(128), dim3(256), 0, stream,
                       in_W, in_b, Wih_f, b_f, Wih_b, b_b, Wc, bc);
    hipLaunchKernelGGL(k_prep_misc, dim3(256), dim3(256), 0, stream,
                       Whh_f, Whh_b, out_W, Whh_bf, outW_bf);
    hipLaunchKernelGGL(k_gemm_p, dim3(1024, 4), dim3(512), 0, stream,
                       source, Wc, bc, P2);
    hipLaunchKernelGGL(k_lstm, dim3(4), dim3(256), 0, stream,
                       P2, Whh_bf, h0, c0, H);
    hipLaunchKernelGGL(k_feats, dim3(1024), dim3(256), 0, stream,
                       H, outW_bf, out_b, feats);
    hipLaunchKernelGGL(k_viterbi, dim3(32), dim3(64), 0, stream,
                       feats, trans, out);
}

// Round 10
// 1925.502 us; speedup vs baseline: 1.9819x; 1.9819x over previous
//
#include <hip/hip_runtime.h>
#include <hip/hip_bf16.h>

typedef __attribute__((ext_vector_type(8))) short bf16x8;
typedef __attribute__((ext_vector_type(4))) float f32x4;
typedef __attribute__((ext_vector_type(4))) unsigned u32x4;
typedef __attribute__((ext_vector_type(2))) unsigned u32x2;

#define SEQT 2048
#define BATCH 32
#define INDIM 512
#define EMB 256
#define HHX 128
#define LBL 16
#define LOG2E 1.44269504f

__device__ __forceinline__ unsigned short f2bf(float f) {
    unsigned u = __float_as_uint(f);
    u += 0x7FFFu + ((u >> 16) & 1u);
    return (unsigned short)(u >> 16);
}
#define BLO(u) __uint_as_float((u) << 16)
#define BHI(u) __uint_as_float((u) & 0xffff0000u)

// Fused-denominator cell: 5 exp2 + 2 rcp. Inputs pre-scaled (-LOG2E for i,f,o;
// +2*LOG2E for g). Clamps keep every factor finite -> NaN-proof saturation.
__device__ __forceinline__ float cell(float ig, float fg, float gg, float og, float& c) {
    float Ef = __builtin_amdgcn_exp2f(fminf(fg, 30.f));
    float Ei = __builtin_amdgcn_exp2f(fminf(ig, 30.f));
    float Eg = __builtin_amdgcn_exp2f(fminf(gg, 60.f));
    float Eo = __builtin_amdgcn_exp2f(fminf(og, 30.f));
    float pf = 1.f + Ef;
    float t1 = (Eg + 1.f) * (1.f + Ei);
    float num = c * t1 + (Eg - 1.f) * pf;
    float cn = num * __builtin_amdgcn_rcpf(pf * t1);
    c = cn;
    float E2 = __builtin_amdgcn_exp2f(fminf(2.f * LOG2E * cn, 60.f));
    float r3 = __builtin_amdgcn_rcpf((E2 + 1.f) * (1.f + Eo));
    return (E2 - 1.f) * r3;
}

// Gate-row permutation: g' = w*64 + q*16 + r  <->  orig = q*128 + w*16 + r
// q = gate (0=i,1=f,2=g,3=o)
__device__ __forceinline__ int orig_of(int gp) {
    return ((gp >> 4) & 3) * 128 + (gp >> 6) * 16 + (gp & 15);
}
__device__ __forceinline__ float gate_scale(int gp) {
    return (((gp >> 4) & 3) == 2) ? (2.f * LOG2E) : (-LOG2E);
}

// ---------------- prep: combined W (Wih @ in_W) + bias, permuted+scaled rows ----------------
__global__ __launch_bounds__(256) void k_prep_wc(
    const float* __restrict__ in_W, const float* __restrict__ in_b,
    const float* __restrict__ Wih_f, const float* __restrict__ b_f,
    const float* __restrict__ Wih_b, const float* __restrict__ b_b,
    unsigned short* __restrict__ Wc, float* __restrict__ bc)
{
    int G0 = blockIdx.x * 8;         // 128 blocks
    int tid = threadIdx.x;
    __shared__ float wrow[8][EMB];
    for (int e = tid; e < 8 * EMB; e += 256) {
        int r = e >> 8, ee = e & 255;
        int G = G0 + r, dir = G >> 9, gp = G & 511;
        wrow[r][ee] = (dir ? Wih_b : Wih_f)[orig_of(gp) * EMB + ee] * gate_scale(gp);
    }
    __syncthreads();
    for (int k = tid; k < INDIM; k += 256) {
        float acc[8] = {0, 0, 0, 0, 0, 0, 0, 0};
        #pragma unroll 4
        for (int e = 0; e < EMB; ++e) {
            float x = in_W[e * INDIM + k];
            #pragma unroll
            for (int r = 0; r < 8; ++r) acc[r] += wrow[r][e] * x;
        }
        #pragma unroll
        for (int r = 0; r < 8; ++r) Wc[(size_t)(G0 + r) * INDIM + k] = f2bf(acc[r]);
    }
    if (tid < 64) {
        for (int r = 0; r < 8; ++r) {
            float p = 0.f;
            for (int e = tid; e < EMB; e += 64) p += wrow[r][e] * in_b[e];
            for (int off = 32; off; off >>= 1) p += __shfl_xor(p, off);
            if (tid == 0) {
                int G = G0 + r, dir = G >> 9, gp = G & 511;
                bc[G] = (dir ? b_b : b_f)[orig_of(gp)] * gate_scale(gp) + p;
            }
        }
    }
}

// ---------------- prep: bf16 converts (Whh permuted+scaled, out_W) ----------------
__global__ __launch_bounds__(256) void k_prep_misc(
    const float* __restrict__ Whh_f, const float* __restrict__ Whh_b,
    const float* __restrict__ out_W,
    unsigned short* __restrict__ Whh_bf, unsigned short* __restrict__ outW_bf)
{
    int idx = blockIdx.x * 256 + threadIdx.x;
    int stride = gridDim.x * 256;
    for (int i = idx; i < 1024 * HHX; i += stride) {
        int G = i >> 7, k = i & 127;
        int dir = G >> 9, gp = G & 511;
        const float* Whh = dir ? Whh_b : Whh_f;
        Whh_bf[i] = f2bf(Whh[orig_of(gp) * HHX + k] * gate_scale(gp));
    }
    for (int i = idx; i < LBL * 256; i += stride) outW_bf[i] = f2bf(out_W[i]);
}

// ---------------- big GEMM: P2 = S @ Wc^T + bc, written in C=8 LSTM layout ----------------
// P2[((t*2 + dir)*4 + bq)][tid(512)][8 = q*2 + jj]: thread (w,lq,lr) owns cells
// (batch8 = lq*2 + jj, unit = w*16 + lr); its 8 gate pre-acts are contiguous 16B.
__global__ __launch_bounds__(512) void k_gemm_p(
    const float* __restrict__ S, const unsigned short* __restrict__ Wc,
    const float* __restrict__ bc, unsigned short* __restrict__ P2)
{
    int m0 = blockIdx.y * 64;
    int n0 = blockIdx.x * 256;
    int tid = threadIdx.x;
    int w = tid >> 6, l = tid & 63;
    int lr = l & 15, lq = l >> 4;
    int wm = w >> 2, wn = w & 3;

    __shared__ __align__(16) unsigned short Alds[64 * 64];
    __shared__ __align__(16) unsigned short Blds[256 * 64];

    const f32x4 fzero = {0.f, 0.f, 0.f, 0.f};
    f32x4 acc[2][4];
    #pragma unroll
    for (int a = 0; a < 2; ++a)
        #pragma unroll
        for (int b = 0; b < 4; ++b) acc[a][b] = fzero;

    for (int kt = 0; kt < 8; ++kt) {
        { // stage A (convert fp32->bf16 via cvt_pk, XOR-swizzled rows of 128B)
            int r = tid >> 3, c = tid & 7;
            const float* src = S + (size_t)(m0 + r) * INDIM + kt * 64 + c * 8;
            float4 v0 = *(const float4*)src;
            float4 v1 = *(const float4*)(src + 4);
            unsigned g0, g1, g2, g3;
            asm("v_cvt_pk_bf16_f32 %0, %1, %2" : "=v"(g0) : "v"(v0.x), "v"(v0.y));
            asm("v_cvt_pk_bf16_f32 %0, %1, %2" : "=v"(g1) : "v"(v0.z), "v"(v0.w));
            asm("v_cvt_pk_bf16_f32 %0, %1, %2" : "=v"(g2) : "v"(v1.x), "v"(v1.y));
            asm("v_cvt_pk_bf16_f32 %0, %1, %2" : "=v"(g3) : "v"(v1.z), "v"(v1.w));
            u32x4 wv = {g0, g1, g2, g3};
            *(u32x4*)((char*)Alds + r * 128 + ((c * 16) ^ ((r & 7) << 4))) = wv;
        }
        { // stage B
            int r = tid >> 1, h = tid & 1;
            const unsigned short* bs = Wc + (size_t)(n0 + r) * INDIM + kt * 64;
            #pragma unroll
            for (int cc = 0; cc < 4; ++cc) {
                int ch = h * 4 + cc;
                bf16x8 v = *(const bf16x8*)(bs + ch * 8);
                *(bf16x8*)((char*)Blds + r * 128 + ((ch * 16) ^ ((r & 7) << 4))) = v;
            }
        }
        __syncthreads();
        bf16x8 af[2][2], bfv[4][2];
        #pragma unroll
        for (int tm = 0; tm < 2; ++tm)
            #pragma unroll
            for (int kk = 0; kk < 2; ++kk) {
                int ra = wm * 32 + tm * 16 + lr;
                af[tm][kk] = *(const bf16x8*)((char*)Alds + ra * 128 + ((kk * 64 + lq * 16) ^ ((ra & 7) << 4)));
            }
        #pragma unroll
        for (int tn = 0; tn < 4; ++tn)
            #pragma unroll
            for (int kk = 0; kk < 2; ++kk) {
                int rb = wn * 64 + tn * 16 + lr;
                bfv[tn][kk] = *(const bf16x8*)((char*)Blds + rb * 128 + ((kk * 64 + lq * 16) ^ ((rb & 7) << 4)));
            }
        #pragma unroll
        for (int tm = 0; tm < 2; ++tm)
            #pragma unroll
            for (int tn = 0; tn < 4; ++tn)
                #pragma unroll
                for (int kk = 0; kk < 2; ++kk)
                    acc[tm][tn] = __builtin_amdgcn_mfma_f32_16x16x32_bf16(af[tm][kk], bfv[tn][kk], acc[tm][tn], 0, 0, 0);
        __syncthreads();
    }
    // epilogue: batch b = tm*16 + lq*4 + j -> bq = tm*2 + (lq>>1), batch8 = (lq&1)*4 + j.
    // dest thread lq_l = (lq&1)*2 + (j>>1), slot = q2*2 + (j&1): j-pair 01 -> tid0, 23 -> tid0+16.
    #pragma unroll
    for (int tn = 0; tn < 4; ++tn) {
        int n = n0 + wn * 64 + tn * 16 + lr;
        float bias = bc[n];
        int dir2 = n >> 9, nn = n & 511;
        int w2 = nn >> 6, q2 = (nn >> 4) & 3, lr2 = nn & 15;
        #pragma unroll
        for (int tm = 0; tm < 2; ++tm) {
            int t = blockIdx.y * 2 + wm;
            int bq2 = tm * 2 + (lq >> 1);
            int tid0 = w2 * 64 + (lq & 1) * 32 + lr2;
            size_t base = (((size_t)(t * 2 + dir2) * 4 + bq2) * 512 + tid0) * 8 + q2 * 2;
            float f0 = acc[tm][tn][0] + bias, f1 = acc[tm][tn][1] + bias;
            float f2 = acc[tm][tn][2] + bias, f3 = acc[tm][tn][3] + bias;
            unsigned p01, p23;
            asm("v_cvt_pk_bf16_f32 %0, %1, %2" : "=v"(p01) : "v"(f0), "v"(f1));
            asm("v_cvt_pk_bf16_f32 %0, %1, %2" : "=v"(p23) : "v"(f2), "v"(f3));
            *(unsigned*)(P2 + base) = p01;
            *(unsigned*)(P2 + base + 128) = p23;
        }
    }
}

// ---------------- LSTM recurrence: 8 blocks (dir x 4 batch-quads of 8), 512 threads ----------------
// Batches live in A rows rowOf(b) = (b>>1)*4 + (b&1) = {0,1,4,5,8,9,12,13}; rows with
// (r&3)>=2 are zero. Every lane's C rows lq*4+{0,1} are its 2 cells (batch lq*2+jj,
// unit w*16+lr) -- no cross-lane redistribution needed.
__global__ __launch_bounds__(512) void k_lstm(
    const unsigned short* __restrict__ P2, const unsigned short* __restrict__ Whh_bf,
    const float* __restrict__ h0, const float* __restrict__ c0,
    unsigned short* __restrict__ H)
{
    int blk = blockIdx.x;
    int dir = blk >> 2, bq = blk & 3;
    int tid = threadIdx.x;
    int w = tid >> 6, l = tid & 63;
    int lr = l & 15, lq = l >> 4;

    __shared__ __align__(16) unsigned short hbuf[2][16 * 128];
    char* hb = (char*)hbuf;

    // Whh fragments: wave w owns gates q=0..3 of units [w*16, w*16+16)
    bf16x8 bfrag[4][4];
    #pragma unroll
    for (int q = 0; q < 4; ++q)
        #pragma unroll
        for (int ko = 0; ko < 4; ++ko) {
            int row = dir * 512 + w * 64 + q * 16 + lr;
            bfrag[q][ko] = *(const bf16x8*)(Whh_bf + (size_t)row * HHX + ko * 32 + lq * 8);
        }

    int u = w * 16 + lr;
    float cA = c0[(dir * 32 + bq * 8 + lq * 2) * HHX + u];
    float cB = c0[(dir * 32 + bq * 8 + lq * 2 + 1) * HHX + u];

    // stage h0: batch b -> row (b>>1)*4 + (b&1); other rows zero; buf1 zeroed
    for (int e = tid; e < 2048; e += 512) {
        int r = e >> 7, uu = e & 127;
        unsigned short v = 0;
        if ((r & 3) < 2) {
            int b = (r >> 2) * 2 + (r & 3);
            v = f2bf(h0[(dir * 32 + bq * 8 + b) * HHX + uu]);
        }
        int addr = (r * 256 + uu * 2) ^ ((r & 7) << 4);
        *(unsigned short*)(hb + addr) = v;
        *(unsigned short*)(hb + 4096 + addr) = 0;
    }
    __syncthreads();

    // loop-invariant LDS offsets
    const int rd0 = (lr * 256 + 0 * 64 + lq * 16) ^ ((lr & 7) << 4);
    const int rd1 = (lr * 256 + 1 * 64 + lq * 16) ^ ((lr & 7) << 4);
    const int rd2 = (lr * 256 + 2 * 64 + lq * 16) ^ ((lr & 7) << 4);
    const int rd3 = (lr * 256 + 3 * 64 + lq * 16) ^ ((lr & 7) << 4);
    const int rA = lq * 4, rB = lq * 4 + 1;
    const int waA = (rA * 256 + u * 2) ^ ((rA & 7) << 4);
    const int waB = (rB * 256 + u * 2) ^ ((rB & 7) << 4);

    int t0 = dir ? (SEQT - 1) : 0;
    const long long pstep = (dir ? -1LL : 1LL) * (2LL * 4 * 512 * 8);
    const unsigned short* pptr = P2 + (((size_t)(t0 * 2 + dir) * 4 + bq) * 512 + tid) * 8;
    bf16x8 pc = *(const bf16x8*)pptr;
    pptr += pstep;

    unsigned short* hpA = H + ((size_t)t0 * 32 + bq * 8 + lq * 2) * 256 + dir * 128 + u;
    const long long hstep = (dir ? -1LL : 1LL) * (32 * 256);

// LDS-only barrier: order the h exchange without draining vmcnt (P prefetch +
// H stores stay in flight across steps).
#define LBAR() asm volatile("s_waitcnt lgkmcnt(0)\n\ts_barrier" ::: "memory")

#define STEP(CUR, PF) do { \
    bf16x8 af0 = *(const bf16x8*)(hb + (CUR) * 4096 + rd0); \
    bf16x8 af1 = *(const bf16x8*)(hb + (CUR) * 4096 + rd1); \
    bf16x8 af2 = *(const bf16x8*)(hb + (CUR) * 4096 + rd2); \
    bf16x8 af3 = *(const bf16x8*)(hb + (CUR) * 4096 + rd3); \
    u32x4 u0 = __builtin_bit_cast(u32x4, pc); \
    if (PF) { pc = *(const bf16x8*)pptr; pptr += pstep; } \
    f32x4 a0 = {BLO(u0.x), BHI(u0.x), 0.f, 0.f}; \
    f32x4 a1 = {BLO(u0.y), BHI(u0.y), 0.f, 0.f}; \
    f32x4 a2 = {BLO(u0.z), BHI(u0.z), 0.f, 0.f}; \
    f32x4 a3 = {BLO(u0.w), BHI(u0.w), 0.f, 0.f}; \
    a0 = __builtin_amdgcn_mfma_f32_16x16x32_bf16(af0, bfrag[0][0], a0, 0, 0, 0); \
    a0 = __builtin_amdgcn_mfma_f32_16x16x32_bf16(af1, bfrag[0][1], a0, 0, 0, 0); \
    a0 = __builtin_amdgcn_mfma_f32_16x16x32_bf16(af2, bfrag[0][2], a0, 0, 0, 0); \
    a0 = __builtin_amdgcn_mfma_f32_16x16x32_bf16(af3, bfrag[0][3], a0, 0, 0, 0); \
    a1 = __builtin_amdgcn_mfma_f32_16x16x32_bf16(af0, bfrag[1][0], a1, 0, 0, 0); \
    a1 = __builtin_amdgcn_mfma_f32_16x16x32_bf16(af1, bfrag[1][1], a1, 0, 0, 0); \
    a1 = __builtin_amdgcn_mfma_f32_16x16x32_bf16(af2, bfrag[1][2], a1, 0, 0, 0); \
    a1 = __builtin_amdgcn_mfma_f32_16x16x32_bf16(af3, bfrag[1][3], a1, 0, 0, 0); \
    a2 = __builtin_amdgcn_mfma_f32_16x16x32_bf16(af0, bfrag[2][0], a2, 0, 0, 0); \
    a2 = __builtin_amdgcn_mfma_f32_16x16x32_bf16(af1, bfrag[2][1], a2, 0, 0, 0); \
    a2 = __builtin_amdgcn_mfma_f32_16x16x32_bf16(af2, bfrag[2][2], a2, 0, 0, 0); \
    a2 = __builtin_amdgcn_mfma_f32_16x16x32_bf16(af3, bfrag[2][3], a2, 0, 0, 0); \
    a3 = __builtin_amdgcn_mfma_f32_16x16x32_bf16(af0, bfrag[3][0], a3, 0, 0, 0); \
    a3 = __builtin_amdgcn_mfma_f32_16x16x32_bf16(af1, bfrag[3][1], a3, 0, 0, 0); \
    a3 = __builtin_amdgcn_mfma_f32_16x16x32_bf16(af2, bfrag[3][2], a3, 0, 0, 0); \
    a3 = __builtin_amdgcn_mfma_f32_16x16x32_bf16(af3, bfrag[3][3], a3, 0, 0, 0); \
    float hnA = cell(a0[0], a1[0], a2[0], a3[0], cA); \
    float hnB = cell(a0[1], a1[1], a2[1], a3[1], cB); \
    unsigned pk; \
    asm("v_cvt_pk_bf16_f32 %0, %1, %2" : "=v"(pk) : "v"(hnA), "v"(hnB)); \
    unsigned short sA = (unsigned short)pk, sB = (unsigned short)(pk >> 16); \
    char* wb = hb + (((CUR) ^ 1) * 4096); \
    *(unsigned short*)(wb + waA) = sA; \
    *(unsigned short*)(wb + waB) = sB; \
    hpA[0] = sA; hpA[256] = sB; \
    hpA += hstep; \
    LBAR(); \
} while (0)

    for (int it = 0; it < 1023; ++it) {
        STEP(0, true);
        STEP(1, true);
    }
    STEP(0, true);
    STEP(1, false);
#undef STEP
#undef LBAR
}

// ---------------- feats: F(65536x16) = H @ outW^T + out_b ----------------
__global__ __launch_bounds__(256) void k_feats(
    const unsigned short* __restrict__ H, const unsigned short* __restrict__ outW_bf,
    const float* __restrict__ out_b, float* __restrict__ feats)
{
    int m0 = blockIdx.x * 64;
    int tid = threadIdx.x;
    int w = tid >> 6, l = tid & 63;
    int lr = l & 15, lq = l >> 4;
    __shared__ __align__(16) unsigned short Hl[64 * 256];

    {
        int r = tid >> 2, cb = (tid & 3) * 8;
        #pragma unroll
        for (int cc = 0; cc < 8; ++cc) {
            int c = cb + cc;
            bf16x8 v = *(const bf16x8*)(H + (size_t)(m0 + r) * 256 + c * 8);
            *(bf16x8*)((char*)Hl + r * 512 + ((c * 16) ^ ((r & 7) << 4))) = v;
        }
    }
    bf16x8 bw[8];
    #pragma unroll
    for (int ko = 0; ko < 8; ++ko)
        bw[ko] = *(const bf16x8*)(outW_bf + lr * 256 + ko * 32 + lq * 8);
    __syncthreads();
    int row = w * 16 + lr;
    f32x4 acc = {0.f, 0.f, 0.f, 0.f};
    #pragma unroll
    for (int ko = 0; ko < 8; ++ko) {
        bf16x8 a = *(const bf16x8*)((char*)Hl + row * 512 + ((ko * 64 + lq * 16) ^ ((row & 7) << 4)));
        acc = __builtin_amdgcn_mfma_f32_16x16x32_bf16(a, bw[ko], acc, 0, 0, 0);
    }
    float ob = out_b[lr];
    #pragma unroll
    for (int j = 0; j < 4; ++j) {
        int m = m0 + w * 16 + lq * 4 + j;
        feats[(size_t)m * 16 + lr] = acc[j] + ob;
    }
}

// ---------------- Viterbi: 1 block per batch, 1 wave; DPP reduce + packed backtrack ----------------
template <int CTRL>
__device__ __forceinline__ float dppf(float x) {
    return __int_as_float(__builtin_amdgcn_update_dpp(0, __float_as_int(x), CTRL, 0xF, 0xF, true));
}
template <int CTRL>
__device__ __forceinline__ int dppi(int x) {
    return __builtin_amdgcn_update_dpp(0, x, CTRL, 0xF, 0xF, true);
}

__global__ __launch_bounds__(64) void k_viterbi(
    const float* __restrict__ feats, const float* __restrict__ trans,
    float* __restrict__ out)
{
    int b = blockIdx.x;
    int l = threadIdx.x;
    int i = l >> 2, s = l & 3;          // i = next-label (0..15), s = prev-quad (0..3)
    __shared__ unsigned char bp[SEQT * 16];
    __shared__ __align__(16) float fch[256 * 16];
    __shared__ unsigned long long bp64[SEQT];

    float tr[4];
    #pragma unroll
    for (int m = 0; m < 4; ++m) tr[m] = trans[i * 16 + s * 4 + m];
    float fvloc[4];
    #pragma unroll
    for (int m = 0; m < 4; ++m) fvloc[m] = (s * 4 + m == 0) ? 0.f : -10000.f;

    int ga[4];
    #pragma unroll
    for (int m = 0; m < 4; ++m) ga[m] = (16 * s + 4 * m) * 4;   // bpermute byte addr

    for (int t = 0; t < SEQT; ++t) {
        if ((t & 255) == 0) {
            __syncthreads();
            for (int k = l; k < 256; k += 64) {
                const float4* src = (const float4*)(feats + (size_t)((t + k) * 32 + b) * 16);
                float4 v0 = src[0], v1 = src[1], v2 = src[2], v3 = src[3];
                float4* dst = (float4*)(fch + k * 16);
                dst[0] = v0; dst[1] = v1; dst[2] = v2; dst[3] = v3;
            }
            __syncthreads();
        }
        float best = fvloc[0] + tr[0];
        int bj = s * 4;
        #pragma unroll
        for (int m = 1; m < 4; ++m) {
            float v = fvloc[m] + tr[m];
            if (v > best) { best = v; bj = s * 4 + m; }
        }
        { // quad xor1 via DPP quad_perm [1,0,3,2]
            float ov = dppf<0xB1>(best); int oj = dppi<0xB1>(bj);
            bool take = (ov > best) || (ov == best && oj < bj);
            best = take ? ov : best; bj = take ? oj : bj;
        }
        { // quad xor2 via DPP quad_perm [2,3,0,1]
            float ov = dppf<0x4E>(best); int oj = dppi<0x4E>(bj);
            bool take = (ov > best) || (ov == best && oj < bj);
            best = take ? ov : best; bj = take ? oj : bj;
        }
        float fvn = best + fch[(t & 255) * 16 + i];
        if (s == 0) bp[t * 16 + i] = (unsigned char)bj;
        #pragma unroll
        for (int m = 0; m < 4; ++m)
            fvloc[m] = __int_as_float(__builtin_amdgcn_ds_bpermute(ga[m], __float_as_int(fvn)));
    }
    // termination
    float bestS = fvloc[0] + trans[16 + s * 4];
    int bl = s * 4;
    #pragma unroll
    for (int m = 1; m < 4; ++m) {
        float tv = fvloc[m] + trans[16 + s * 4 + m];
        if (tv > bestS) { bestS = tv; bl = s * 4 + m; }
    }
    {
        float ov = dppf<0xB1>(bestS); int oj = dppi<0xB1>(bl);
        bool take = (ov > bestS) || (ov == bestS && oj < bl);
        bestS = take ? ov : bestS; bl = take ? oj : bl;
    }
    {
        float ov = dppf<0x4E>(bestS); int oj = dppi<0x4E>(bl);
        bool take = (ov > bestS) || (ov == bestS && oj < bl);
        bestS = take ? ov : bestS; bl = take ? oj : bl;
    }
    __syncthreads();
    // pack bp rows into nibble-u64 (address-independent backtrack reads)
    for (int t = l; t < SEQT; t += 64) {
        const uint4* p = (const uint4*)(bp + t * 16);
        uint4 u = *p;
        unsigned n0 = (u.x | (u.x >> 4)) & 0x00FF00FFu; n0 = (n0 | (n0 >> 8)) & 0xFFFFu;
        unsigned n1 = (u.y | (u.y >> 4)) & 0x00FF00FFu; n1 = (n1 | (n1 >> 8)) & 0xFFFFu;
        unsigned n2 = (u.z | (u.z >> 4)) & 0x00FF00FFu; n2 = (n2 | (n2 >> 8)) & 0xFFFFu;
        unsigned n3 = (u.w | (u.w >> 4)) & 0x00FF00FFu; n3 = (n3 | (n3 >> 8)) & 0xFFFFu;
        bp64[t] = (unsigned long long)n0 | ((unsigned long long)n1 << 16)
                | ((unsigned long long)n2 << 32) | ((unsigned long long)n3 << 48);
    }
    __syncthreads();
    if (l == 0) out[b] = bestS;
    // all lanes run the chain redundantly; lane t&63 stores t
    int lbl = bl;
    #pragma unroll 8
    for (int t = SEQT - 1; t >= 0; --t) {
        if ((t & 63) == l) out[32 + (size_t)t * 32 + b] = (float)lbl;
        lbl = (int)((bp64[t] >> (lbl * 4)) & 15ull);
    }
}

extern "C" void kernel_launch(void* const* d_in, const int* in_sizes, int n_in,
                              void* d_out, int out_size, void* d_ws, size_t ws_size,
                              hipStream_t stream) {
    const float* source = (const float*)d_in[0];
    const float* in_W  = (const float*)d_in[1];
    const float* in_b  = (const float*)d_in[2];
    const float* Wih_f = (const float*)d_in[3];
    const float* Whh_f = (const float*)d_in[4];
    const float* b_f   = (const float*)d_in[5];
    const float* Wih_b = (const float*)d_in[6];
    const float* Whh_b = (const float*)d_in[7];
    const float* b_b   = (const float*)d_in[8];
    const float* out_W = (const float*)d_in[9];
    const float* out_b = (const float*)d_in[10];
    const float* trans = (const float*)d_in[11];
    const float* h0    = (const float*)d_in[12];
    const float* c0    = (const float*)d_in[13];
    float* out = (float*)d_out;

    char* ws = (char*)d_ws;
    unsigned short* P2      = (unsigned short*)(ws);                 // 2048*2*4*512*8*2 = 134217728
    unsigned short* H       = (unsigned short*)(ws + 134217728);     // 65536*256*2  =  33554432
    float*          feats   = (float*)         (ws + 167772160);     // 65536*16*4   =   4194304
    unsigned short* Wc      = (unsigned short*)(ws + 171966464);     // 1024*512*2   =   1048576
    float*          bc      = (float*)         (ws + 173015040);     // 1024*4
    unsigned short* Whh_bf  = (unsigned short*)(ws + 173019136);     // 1024*128*2   =    262144
    unsigned short* outW_bf = (unsigned short*)(ws + 173281280);     // 16*256*2
    // total ~173.3 MB

    hipLaunchKernelGGL(k_prep_wc, dim3(128), dim3(256), 0, stream,
                       in_W, in_b, Wih_f, b_f, Wih_b, b_b, Wc, bc);
    hipLaunchKernelGGL(k_prep_misc, dim3(256), dim3(256), 0, stream,
                       Whh_f, Whh_b, out_W, Whh_bf, outW_bf);
    hipLaunchKernelGGL(k_gemm_p, dim3(4, 1024), dim3(512), 0, stream,
                       source, Wc, bc, P2);
    hipLaunchKernelGGL(k_lstm, dim3(8), dim3(512), 0, stream,
                       P2, Whh_bf, h0, c0, H);
    hipLaunchKernelGGL(k_feats, dim3(1024), dim3(256), 0, stream,
                       H, outW_bf, out_b, feats);
    hipLaunchKernelGGL(k_viterbi, dim3(32), dim3(64), 0, stream,
                       feats, trans, out);
}

// Round 11
// 1824.430 us; speedup vs baseline: 2.0917x; 1.0554x over previous
//
#include <hip/hip_runtime.h>
#include <hip/hip_bf16.h>

typedef __attribute__((ext_vector_type(8))) short bf16x8;
typedef __attribute__((ext_vector_type(4))) float f32x4;
typedef __attribute__((ext_vector_type(4))) unsigned u32x4;
typedef __attribute__((ext_vector_type(2))) unsigned u32x2;

#define SEQT 2048
#define BATCH 32
#define INDIM 512
#define EMB 256
#define HHX 128
#define LBL 16
#define LOG2E 1.44269504f

__device__ __forceinline__ unsigned short f2bf(float f) {
    unsigned u = __float_as_uint(f);
    u += 0x7FFFu + ((u >> 16) & 1u);
    return (unsigned short)(u >> 16);
}
#define BLO(u) __uint_as_float((u) << 16)
#define BHI(u) __uint_as_float((u) & 0xffff0000u)

// Fused-denominator cell: 5 exp2 + 2 rcp. Inputs pre-scaled (-LOG2E for i,f,o;
// +2*LOG2E for g). Clamps keep every factor finite -> NaN-proof saturation.
__device__ __forceinline__ float cell(float ig, float fg, float gg, float og, float& c) {
    float Ef = __builtin_amdgcn_exp2f(fminf(fg, 30.f));
    float Ei = __builtin_amdgcn_exp2f(fminf(ig, 30.f));
    float Eg = __builtin_amdgcn_exp2f(fminf(gg, 60.f));
    float Eo = __builtin_amdgcn_exp2f(fminf(og, 30.f));
    float pf = 1.f + Ef;
    float t1 = (Eg + 1.f) * (1.f + Ei);
    float num = c * t1 + (Eg - 1.f) * pf;
    float cn = num * __builtin_amdgcn_rcpf(pf * t1);
    c = cn;
    float E2 = __builtin_amdgcn_exp2f(fminf(2.f * LOG2E * cn, 60.f));
    float r3 = __builtin_amdgcn_rcpf((E2 + 1.f) * (1.f + Eo));
    return (E2 - 1.f) * r3;
}

// Gate-row permutation: g' = w*64 + q*16 + r  <->  orig = q*128 + w*16 + r
// q = gate (0=i,1=f,2=g,3=o)
__device__ __forceinline__ int orig_of(int gp) {
    return ((gp >> 4) & 3) * 128 + (gp >> 6) * 16 + (gp & 15);
}
__device__ __forceinline__ float gate_scale(int gp) {
    return (((gp >> 4) & 3) == 2) ? (2.f * LOG2E) : (-LOG2E);
}

// ---------------- prep: combined W (Wih @ in_W) + bias, permuted+scaled rows ----------------
__global__ __launch_bounds__(256) void k_prep_wc(
    const float* __restrict__ in_W, const float* __restrict__ in_b,
    const float* __restrict__ Wih_f, const float* __restrict__ b_f,
    const float* __restrict__ Wih_b, const float* __restrict__ b_b,
    unsigned short* __restrict__ Wc, float* __restrict__ bc)
{
    int G0 = blockIdx.x * 8;         // 128 blocks
    int tid = threadIdx.x;
    __shared__ float wrow[8][EMB];
    for (int e = tid; e < 8 * EMB; e += 256) {
        int r = e >> 8, ee = e & 255;
        int G = G0 + r, dir = G >> 9, gp = G & 511;
        wrow[r][ee] = (dir ? Wih_b : Wih_f)[orig_of(gp) * EMB + ee] * gate_scale(gp);
    }
    __syncthreads();
    for (int k = tid; k < INDIM; k += 256) {
        float acc[8] = {0, 0, 0, 0, 0, 0, 0, 0};
        #pragma unroll 4
        for (int e = 0; e < EMB; ++e) {
            float x = in_W[e * INDIM + k];
            #pragma unroll
            for (int r = 0; r < 8; ++r) acc[r] += wrow[r][e] * x;
        }
        #pragma unroll
        for (int r = 0; r < 8; ++r) Wc[(size_t)(G0 + r) * INDIM + k] = f2bf(acc[r]);
    }
    if (tid < 64) {
        for (int r = 0; r < 8; ++r) {
            float p = 0.f;
            for (int e = tid; e < EMB; e += 64) p += wrow[r][e] * in_b[e];
            for (int off = 32; off; off >>= 1) p += __shfl_xor(p, off);
            if (tid == 0) {
                int G = G0 + r, dir = G >> 9, gp = G & 511;
                bc[G] = (dir ? b_b : b_f)[orig_of(gp)] * gate_scale(gp) + p;
            }
        }
    }
}

// ---------------- prep: bf16 converts (Whh permuted+scaled, out_W) ----------------
__global__ __launch_bounds__(256) void k_prep_misc(
    const float* __restrict__ Whh_f, const float* __restrict__ Whh_b,
    const float* __restrict__ out_W,
    unsigned short* __restrict__ Whh_bf, unsigned short* __restrict__ outW_bf)
{
    int idx = blockIdx.x * 256 + threadIdx.x;
    int stride = gridDim.x * 256;
    for (int i = idx; i < 1024 * HHX; i += stride) {
        int G = i >> 7, k = i & 127;
        int dir = G >> 9, gp = G & 511;
        const float* Whh = dir ? Whh_b : Whh_f;
        Whh_bf[i] = f2bf(Whh[orig_of(gp) * HHX + k] * gate_scale(gp));
    }
    for (int i = idx; i < LBL * 256; i += stride) outW_bf[i] = f2bf(out_W[i]);
}

// ---------------- big GEMM: P2 = S @ Wc^T + bc, written in C=4 LSTM layout ----------------
// P2[((t*2 + dir)*8 + bq)][tid(512)][4 = gate q]: thread (w,lq,lr) owns cell
// (batch4 = lq, unit = w*16 + lr); its 4 gate pre-acts are contiguous 8B.
__global__ __launch_bounds__(512) void k_gemm_p(
    const float* __restrict__ S, const unsigned short* __restrict__ Wc,
    const float* __restrict__ bc, unsigned short* __restrict__ P2)
{
    int m0 = blockIdx.y * 64;
    int n0 = blockIdx.x * 256;
    int tid = threadIdx.x;
    int w = tid >> 6, l = tid & 63;
    int lr = l & 15, lq = l >> 4;
    int wm = w >> 2, wn = w & 3;

    __shared__ __align__(16) unsigned short Alds[64 * 64];
    __shared__ __align__(16) unsigned short Blds[256 * 64];

    const f32x4 fzero = {0.f, 0.f, 0.f, 0.f};
    f32x4 acc[2][4];
    #pragma unroll
    for (int a = 0; a < 2; ++a)
        #pragma unroll
        for (int b = 0; b < 4; ++b) acc[a][b] = fzero;

    for (int kt = 0; kt < 8; ++kt) {
        { // stage A (convert fp32->bf16 via cvt_pk, XOR-swizzled rows of 128B)
            int r = tid >> 3, c = tid & 7;
            const float* src = S + (size_t)(m0 + r) * INDIM + kt * 64 + c * 8;
            float4 v0 = *(const float4*)src;
            float4 v1 = *(const float4*)(src + 4);
            unsigned g0, g1, g2, g3;
            asm("v_cvt_pk_bf16_f32 %0, %1, %2" : "=v"(g0) : "v"(v0.x), "v"(v0.y));
            asm("v_cvt_pk_bf16_f32 %0, %1, %2" : "=v"(g1) : "v"(v0.z), "v"(v0.w));
            asm("v_cvt_pk_bf16_f32 %0, %1, %2" : "=v"(g2) : "v"(v1.x), "v"(v1.y));
            asm("v_cvt_pk_bf16_f32 %0, %1, %2" : "=v"(g3) : "v"(v1.z), "v"(v1.w));
            u32x4 wv = {g0, g1, g2, g3};
            *(u32x4*)((char*)Alds + r * 128 + ((c * 16) ^ ((r & 7) << 4))) = wv;
        }
        { // stage B
            int r = tid >> 1, h = tid & 1;
            const unsigned short* bs = Wc + (size_t)(n0 + r) * INDIM + kt * 64;
            #pragma unroll
            for (int cc = 0; cc < 4; ++cc) {
                int ch = h * 4 + cc;
                bf16x8 v = *(const bf16x8*)(bs + ch * 8);
                *(bf16x8*)((char*)Blds + r * 128 + ((ch * 16) ^ ((r & 7) << 4))) = v;
            }
        }
        __syncthreads();
        bf16x8 af[2][2], bfv[4][2];
        #pragma unroll
        for (int tm = 0; tm < 2; ++tm)
            #pragma unroll
            for (int kk = 0; kk < 2; ++kk) {
                int ra = wm * 32 + tm * 16 + lr;
                af[tm][kk] = *(const bf16x8*)((char*)Alds + ra * 128 + ((kk * 64 + lq * 16) ^ ((ra & 7) << 4)));
            }
        #pragma unroll
        for (int tn = 0; tn < 4; ++tn)
            #pragma unroll
            for (int kk = 0; kk < 2; ++kk) {
                int rb = wn * 64 + tn * 16 + lr;
                bfv[tn][kk] = *(const bf16x8*)((char*)Blds + rb * 128 + ((kk * 64 + lq * 16) ^ ((rb & 7) << 4)));
            }
        #pragma unroll
        for (int tm = 0; tm < 2; ++tm)
            #pragma unroll
            for (int tn = 0; tn < 4; ++tn)
                #pragma unroll
                for (int kk = 0; kk < 2; ++kk)
                    acc[tm][tn] = __builtin_amdgcn_mfma_f32_16x16x32_bf16(af[tm][kk], bfv[tn][kk], acc[tm][tn], 0, 0, 0);
        __syncthreads();
    }
    // epilogue: m = m0 + wm*32 + tm*16 + lq*4 + j -> t = m>>5, bq = tm*4 + lq,
    // dest thread = w2*64 + j*16 + lr2, slot = gate q2. 4 x 2B stores per (tn,tm).
    #pragma unroll
    for (int tn = 0; tn < 4; ++tn) {
        int n = n0 + wn * 64 + tn * 16 + lr;
        float bias = bc[n];
        int dir2 = n >> 9, nn = n & 511;
        int w2 = nn >> 6, q2 = (nn >> 4) & 3, lr2 = nn & 15;
        #pragma unroll
        for (int tm = 0; tm < 2; ++tm) {
            int t = blockIdx.y * 2 + wm;
            int bq2 = tm * 4 + lq;
            size_t fr = ((size_t)(t * 2 + dir2) * 8 + bq2) * 512;
            float f0 = acc[tm][tn][0] + bias, f1 = acc[tm][tn][1] + bias;
            float f2 = acc[tm][tn][2] + bias, f3 = acc[tm][tn][3] + bias;
            unsigned p01, p23;
            asm("v_cvt_pk_bf16_f32 %0, %1, %2" : "=v"(p01) : "v"(f0), "v"(f1));
            asm("v_cvt_pk_bf16_f32 %0, %1, %2" : "=v"(p23) : "v"(f2), "v"(f3));
            P2[(fr + (w2 * 64 + 0 * 16 + lr2)) * 4 + q2] = (unsigned short)p01;
            P2[(fr + (w2 * 64 + 1 * 16 + lr2)) * 4 + q2] = (unsigned short)(p01 >> 16);
            P2[(fr + (w2 * 64 + 2 * 16 + lr2)) * 4 + q2] = (unsigned short)p23;
            P2[(fr + (w2 * 64 + 3 * 16 + lr2)) * 4 + q2] = (unsigned short)(p23 >> 16);
        }
    }
}

// ---------------- LSTM recurrence: 16 blocks (dir x 8 batch-quads of 4), 512 threads ----------------
// Batches live in A rows rowOf(b) = b*4 = {0,4,8,12}; other rows zero. Every lane's
// C row lq*4+0 is its single cell (batch lq, unit w*16+lr) -- no cross-lane traffic.
__global__ __launch_bounds__(512) void k_lstm(
    const unsigned short* __restrict__ P2, const unsigned short* __restrict__ Whh_bf,
    const float* __restrict__ h0, const float* __restrict__ c0,
    unsigned short* __restrict__ H)
{
    int blk = blockIdx.x;
    int dir = blk >> 3, bq = blk & 7;
    int tid = threadIdx.x;
    int w = tid >> 6, l = tid & 63;
    int lr = l & 15, lq = l >> 4;

    __shared__ __align__(16) unsigned short hbuf[2][16 * 128];
    char* hb = (char*)hbuf;

    // Whh fragments: wave w owns gates q=0..3 of units [w*16, w*16+16)
    bf16x8 bfrag[4][4];
    #pragma unroll
    for (int q = 0; q < 4; ++q)
        #pragma unroll
        for (int ko = 0; ko < 4; ++ko) {
            int row = dir * 512 + w * 64 + q * 16 + lr;
            bfrag[q][ko] = *(const bf16x8*)(Whh_bf + (size_t)row * HHX + ko * 32 + lq * 8);
        }

    int u = w * 16 + lr;
    float cA = c0[(dir * 32 + bq * 4 + lq) * HHX + u];

    // stage h0: batch b -> row b*4; other rows zero; buf1 zeroed
    for (int e = tid; e < 2048; e += 512) {
        int r = e >> 7, uu = e & 127;
        unsigned short v = 0;
        if ((r & 3) == 0) {
            int b = r >> 2;
            v = f2bf(h0[(dir * 32 + bq * 4 + b) * HHX + uu]);
        }
        int addr = (r * 256 + uu * 2) ^ ((r & 7) << 4);
        *(unsigned short*)(hb + addr) = v;
        *(unsigned short*)(hb + 4096 + addr) = 0;
    }
    __syncthreads();

    // loop-invariant LDS offsets
    const int rd0 = (lr * 256 + 0 * 64 + lq * 16) ^ ((lr & 7) << 4);
    const int rd1 = (lr * 256 + 1 * 64 + lq * 16) ^ ((lr & 7) << 4);
    const int rd2 = (lr * 256 + 2 * 64 + lq * 16) ^ ((lr & 7) << 4);
    const int rd3 = (lr * 256 + 3 * 64 + lq * 16) ^ ((lr & 7) << 4);
    const int rA = lq * 4;
    const int waA = (rA * 256 + u * 2) ^ ((rA & 7) << 4);

    int t0 = dir ? (SEQT - 1) : 0;
    const long long pstep = (dir ? -1LL : 1LL) * (2LL * 8 * 512 * 4);
    const unsigned short* pptr = P2 + (((size_t)(t0 * 2 + dir) * 8 + bq) * 512 + tid) * 4;
    u32x2 pc = *(const u32x2*)pptr;
    pptr += pstep;

    unsigned short* hpA = H + ((size_t)t0 * 32 + bq * 4 + lq) * 256 + dir * 128 + u;
    const long long hstep = (dir ? -1LL : 1LL) * (32 * 256);

// LDS-only barrier: order the h exchange without draining vmcnt (P prefetch +
// H stores stay in flight across steps).
#define LBAR() asm volatile("s_waitcnt lgkmcnt(0)\n\ts_barrier" ::: "memory")

#define STEP(CUR, PF) do { \
    bf16x8 af0 = *(const bf16x8*)(hb + (CUR) * 4096 + rd0); \
    bf16x8 af1 = *(const bf16x8*)(hb + (CUR) * 4096 + rd1); \
    bf16x8 af2 = *(const bf16x8*)(hb + (CUR) * 4096 + rd2); \
    bf16x8 af3 = *(const bf16x8*)(hb + (CUR) * 4096 + rd3); \
    u32x2 u0 = pc; \
    if (PF) { pc = *(const u32x2*)pptr; pptr += pstep; } \
    f32x4 a0 = {BLO(u0.x), 0.f, 0.f, 0.f}; \
    f32x4 a1 = {BHI(u0.x), 0.f, 0.f, 0.f}; \
    f32x4 a2 = {BLO(u0.y), 0.f, 0.f, 0.f}; \
    f32x4 a3 = {BHI(u0.y), 0.f, 0.f, 0.f}; \
    a0 = __builtin_amdgcn_mfma_f32_16x16x32_bf16(af0, bfrag[0][0], a0, 0, 0, 0); \
    a0 = __builtin_amdgcn_mfma_f32_16x16x32_bf16(af1, bfrag[0][1], a0, 0, 0, 0); \
    a0 = __builtin_amdgcn_mfma_f32_16x16x32_bf16(af2, bfrag[0][2], a0, 0, 0, 0); \
    a0 = __builtin_amdgcn_mfma_f32_16x16x32_bf16(af3, bfrag[0][3], a0, 0, 0, 0); \
    a1 = __builtin_amdgcn_mfma_f32_16x16x32_bf16(af0, bfrag[1][0], a1, 0, 0, 0); \
    a1 = __builtin_amdgcn_mfma_f32_16x16x32_bf16(af1, bfrag[1][1], a1, 0, 0, 0); \
    a1 = __builtin_amdgcn_mfma_f32_16x16x32_bf16(af2, bfrag[1][2], a1, 0, 0, 0); \
    a1 = __builtin_amdgcn_mfma_f32_16x16x32_bf16(af3, bfrag[1][3], a1, 0, 0, 0); \
    a2 = __builtin_amdgcn_mfma_f32_16x16x32_bf16(af0, bfrag[2][0], a2, 0, 0, 0); \
    a2 = __builtin_amdgcn_mfma_f32_16x16x32_bf16(af1, bfrag[2][1], a2, 0, 0, 0); \
    a2 = __builtin_amdgcn_mfma_f32_16x16x32_bf16(af2, bfrag[2][2], a2, 0, 0, 0); \
    a2 = __builtin_amdgcn_mfma_f32_16x16x32_bf16(af3, bfrag[2][3], a2, 0, 0, 0); \
    a3 = __builtin_amdgcn_mfma_f32_16x16x32_bf16(af0, bfrag[3][0], a3, 0, 0, 0); \
    a3 = __builtin_amdgcn_mfma_f32_16x16x32_bf16(af1, bfrag[3][1], a3, 0, 0, 0); \
    a3 = __builtin_amdgcn_mfma_f32_16x16x32_bf16(af2, bfrag[3][2], a3, 0, 0, 0); \
    a3 = __builtin_amdgcn_mfma_f32_16x16x32_bf16(af3, bfrag[3][3], a3, 0, 0, 0); \
    float hnA = cell(a0[0], a1[0], a2[0], a3[0], cA); \
    unsigned pk; \
    asm("v_cvt_pk_bf16_f32 %0, %1, %2" : "=v"(pk) : "v"(hnA), "v"(hnA)); \
    unsigned short sA = (unsigned short)pk; \
    *(unsigned short*)(hb + (((CUR) ^ 1) * 4096) + waA) = sA; \
    hpA[0] = sA; \
    hpA += hstep; \
    LBAR(); \
} while (0)

    for (int it = 0; it < 1023; ++it) {
        STEP(0, true);
        STEP(1, true);
    }
    STEP(0, true);
    STEP(1, false);
#undef STEP
#undef LBAR
}

// ---------------- feats: F(65536x16) = H @ outW^T + out_b ----------------
__global__ __launch_bounds__(256) void k_feats(
    const unsigned short* __restrict__ H, const unsigned short* __restrict__ outW_bf,
    const float* __restrict__ out_b, float* __restrict__ feats)
{
    int m0 = blockIdx.x * 64;
    int tid = threadIdx.x;
    int w = tid >> 6, l = tid & 63;
    int lr = l & 15, lq = l >> 4;
    __shared__ __align__(16) unsigned short Hl[64 * 256];

    {
        int r = tid >> 2, cb = (tid & 3) * 8;
        #pragma unroll
        for (int cc = 0; cc < 8; ++cc) {
            int c = cb + cc;
            bf16x8 v = *(const bf16x8*)(H + (size_t)(m0 + r) * 256 + c * 8);
            *(bf16x8*)((char*)Hl + r * 512 + ((c * 16) ^ ((r & 7) << 4))) = v;
        }
    }
    bf16x8 bw[8];
    #pragma unroll
    for (int ko = 0; ko < 8; ++ko)
        bw[ko] = *(const bf16x8*)(outW_bf + lr * 256 + ko * 32 + lq * 8);
    __syncthreads();
    int row = w * 16 + lr;
    f32x4 acc = {0.f, 0.f, 0.f, 0.f};
    #pragma unroll
    for (int ko = 0; ko < 8; ++ko) {
        bf16x8 a = *(const bf16x8*)((char*)Hl + row * 512 + ((ko * 64 + lq * 16) ^ ((row & 7) << 4)));
        acc = __builtin_amdgcn_mfma_f32_16x16x32_bf16(a, bw[ko], acc, 0, 0, 0);
    }
    float ob = out_b[lr];
    #pragma unroll
    for (int j = 0; j < 4; ++j) {
        int m = m0 + w * 16 + lq * 4 + j;
        feats[(size_t)m * 16 + lr] = acc[j] + ob;
    }
}

// ---------------- Viterbi: 1 block per batch, 1 wave; DPP reduce + packed backtrack ----------------
template <int CTRL>
__device__ __forceinline__ float dppf(float x) {
    return __int_as_float(__builtin_amdgcn_update_dpp(0, __float_as_int(x), CTRL, 0xF, 0xF, true));
}
template <int CTRL>
__device__ __forceinline__ int dppi(int x) {
    return __builtin_amdgcn_update_dpp(0, x, CTRL, 0xF, 0xF, true);
}

__global__ __launch_bounds__(64) void k_viterbi(
    const float* __restrict__ feats, const float* __restrict__ trans,
    float* __restrict__ out)
{
    int b = blockIdx.x;
    int l = threadIdx.x;
    int i = l >> 2, s = l & 3;          // i = next-label (0..15), s = prev-quad (0..3)
    __shared__ unsigned char bp[SEQT * 16];
    __shared__ __align__(16) float fch[256 * 16];
    __shared__ unsigned long long bp64[SEQT];

    float tr[4];
    #pragma unroll
    for (int m = 0; m < 4; ++m) tr[m] = trans[i * 16 + s * 4 + m];
    float fvloc[4];
    #pragma unroll
    for (int m = 0; m < 4; ++m) fvloc[m] = (s * 4 + m == 0) ? 0.f : -10000.f;

    int ga[4];
    #pragma unroll
    for (int m = 0; m < 4; ++m) ga[m] = (16 * s + 4 * m) * 4;   // bpermute byte addr

    for (int t = 0; t < SEQT; ++t) {
        if ((t & 255) == 0) {
            __syncthreads();
            for (int k = l; k < 256; k += 64) {
                const float4* src = (const float4*)(feats + (size_t)((t + k) * 32 + b) * 16);
                float4 v0 = src[0], v1 = src[1], v2 = src[2], v3 = src[3];
                float4* dst = (float4*)(fch + k * 16);
                dst[0] = v0; dst[1] = v1; dst[2] = v2; dst[3] = v3;
            }
            __syncthreads();
        }
        float best = fvloc[0] + tr[0];
        int bj = s * 4;
        #pragma unroll
        for (int m = 1; m < 4; ++m) {
            float v = fvloc[m] + tr[m];
            if (v > best) { best = v; bj = s * 4 + m; }
        }
        { // quad xor1 via DPP quad_perm [1,0,3,2]
            float ov = dppf<0xB1>(best); int oj = dppi<0xB1>(bj);
            bool take = (ov > best) || (ov == best && oj < bj);
            best = take ? ov : best; bj = take ? oj : bj;
        }
        { // quad xor2 via DPP quad_perm [2,3,0,1]
            float ov = dppf<0x4E>(best); int oj = dppi<0x4E>(bj);
            bool take = (ov > best) || (ov == best && oj < bj);
            best = take ? ov : best; bj = take ? oj : bj;
        }
        float fvn = best + fch[(t & 255) * 16 + i];
        if (s == 0) bp[t * 16 + i] = (unsigned char)bj;
        #pragma unroll
        for (int m = 0; m < 4; ++m)
            fvloc[m] = __int_as_float(__builtin_amdgcn_ds_bpermute(ga[m], __float_as_int(fvn)));
    }
    // termination
    float bestS = fvloc[0] + trans[16 + s * 4];
    int bl = s * 4;
    #pragma unroll
    for (int m = 1; m < 4; ++m) {
        float tv = fvloc[m] + trans[16 + s * 4 + m];
        if (tv > bestS) { bestS = tv; bl = s * 4 + m; }
    }
    {
        float ov = dppf<0xB1>(bestS); int oj = dppi<0xB1>(bl);
        bool take = (ov > bestS) || (ov == bestS && oj < bl);
        bestS = take ? ov : bestS; bl = take ? oj : bl;
    }
    {
        float ov = dppf<0x4E>(bestS); int oj = dppi<0x4E>(bl);
        bool take = (ov > bestS) || (ov == bestS && oj < bl);
        bestS = take ? ov : bestS; bl = take ? oj : bl;
    }
    __syncthreads();
    // pack bp rows into nibble-u64 (address-independent backtrack reads)
    for (int t = l; t < SEQT; t += 64) {
        const uint4* p = (const uint4*)(bp + t * 16);
        uint4 u = *p;
        unsigned n0 = (u.x | (u.x >> 4)) & 0x00FF00FFu; n0 = (n0 | (n0 >> 8)) & 0xFFFFu;
        unsigned n1 = (u.y | (u.y >> 4)) & 0x00FF00FFu; n1 = (n1 | (n1 >> 8)) & 0xFFFFu;
        unsigned n2 = (u.z | (u.z >> 4)) & 0x00FF00FFu; n2 = (n2 | (n2 >> 8)) & 0xFFFFu;
        unsigned n3 = (u.w | (u.w >> 4)) & 0x00FF00FFu; n3 = (n3 | (n3 >> 8)) & 0xFFFFu;
        bp64[t] = (unsigned long long)n0 | ((unsigned long long)n1 << 16)
                | ((unsigned long long)n2 << 32) | ((unsigned long long)n3 << 48);
    }
    __syncthreads();
    if (l == 0) out[b] = bestS;
    // all lanes run the chain redundantly; lane t&63 stores t
    int lbl = bl;
    #pragma unroll 8
    for (int t = SEQT - 1; t >= 0; --t) {
        if ((t & 63) == l) out[32 + (size_t)t * 32 + b] = (float)lbl;
        lbl = (int)((bp64[t] >> (lbl * 4)) & 15ull);
    }
}

extern "C" void kernel_launch(void* const* d_in, const int* in_sizes, int n_in,
                              void* d_out, int out_size, void* d_ws, size_t ws_size,
                              hipStream_t stream) {
    const float* source = (const float*)d_in[0];
    const float* in_W  = (const float*)d_in[1];
    const float* in_b  = (const float*)d_in[2];
    const float* Wih_f = (const float*)d_in[3];
    const float* Whh_f = (const float*)d_in[4];
    const float* b_f   = (const float*)d_in[5];
    const float* Wih_b = (const float*)d_in[6];
    const float* Whh_b = (const float*)d_in[7];
    const float* b_b   = (const float*)d_in[8];
    const float* out_W = (const float*)d_in[9];
    const float* out_b = (const float*)d_in[10];
    const float* trans = (const float*)d_in[11];
    const float* h0    = (const float*)d_in[12];
    const float* c0    = (const float*)d_in[13];
    float* out = (float*)d_out;

    char* ws = (char*)d_ws;
    unsigned short* P2      = (unsigned short*)(ws);                 // 2048*2*8*512*4*2 = 134217728
    unsigned short* H       = (unsigned short*)(ws + 134217728);     // 65536*256*2  =  33554432
    float*          feats   = (float*)         (ws + 167772160);     // 65536*16*4   =   4194304
    unsigned short* Wc      = (unsigned short*)(ws + 171966464);     // 1024*512*2   =   1048576
    float*          bc      = (float*)         (ws + 173015040);     // 1024*4
    unsigned short* Whh_bf  = (unsigned short*)(ws + 173019136);     // 1024*128*2   =    262144
    unsigned short* outW_bf = (unsigned short*)(ws + 173281280);     // 16*256*2
    // total ~173.3 MB

    hipLaunchKernelGGL(k_prep_wc, dim3(128), dim3(256), 0, stream,
                       in_W, in_b, Wih_f, b_f, Wih_b, b_b, Wc, bc);
    hipLaunchKernelGGL(k_prep_misc, dim3(256), dim3(256), 0, stream,
                       Whh_f, Whh_b, out_W, Whh_bf, outW_bf);
    hipLaunchKernelGGL(k_gemm_p, dim3(4, 1024), dim3(512), 0, stream,
                       source, Wc, bc, P2);
    hipLaunchKernelGGL(k_lstm, dim3(16), dim3(512), 0, stream,
                       P2, Whh_bf, h0, c0, H);
    hipLaunchKernelGGL(k_feats, dim3(1024), dim3(256), 0, stream,
                       H, outW_bf, out_b, feats);
    hipLaunchKernelGGL(k_viterbi, dim3(32), dim3(64), 0, stream,
                       feats, trans, out);
}